// Round 2
// baseline (889.843 us; speedup 1.0000x reference)
//
#include <hip/hip_runtime.h>
#include <hip/hip_bf16.h>
#include <math.h>

#define NH 8
#define L 512
#define DR 384
#define DP 128
#define DS 16
#define DCAT 1280
#define TJ 32            // j-tile (rows of e per tile)
#define NTILE 16         // 512 / 32

#define SCALE_SCALAR 0.25f
#define SCALE_POINT  0.23570226039551584f   // (4.5*4)^-0.5
#define SCALE_TOTAL  0.5773502691896258f    // 3^-0.5

typedef __bf16 bf16_t;
typedef bf16_t bf16x8 __attribute__((ext_vector_type(8)));
typedef float  f32x4v __attribute__((ext_vector_type(4)));

__device__ __forceinline__ void cp_g2l_16(const void* g, void* l) {
    __builtin_amdgcn_global_load_lds(
        (const __attribute__((address_space(1))) unsigned int*)g,
        (__attribute__((address_space(3))) unsigned int*)l, 16, 0, 0);
}

// ---------------------------------------------------------------------------
// k_pack: x -> bf16 (row-major 1024x384), all six W -> WallT (672x384 bf16, N-major)
// ---------------------------------------------------------------------------
__global__ __launch_bounds__(256) void k_pack(
    const float* __restrict__ x,
    const float* __restrict__ Wq_s, const float* __restrict__ Wk_s, const float* __restrict__ Wv_s,
    const float* __restrict__ Wq_p, const float* __restrict__ Wk_p, const float* __restrict__ Wv_p,
    __hip_bfloat16* __restrict__ xb, __hip_bfloat16* __restrict__ WallT) {
    int idx = blockIdx.x * 256 + threadIdx.x;          // 651264 total
    const int T1 = 1024 * 384;
    if (idx < T1) {
        xb[idx] = __float2bfloat16(x[idx]);
    } else {
        int j = idx - T1;                              // 0 .. 258047
        int n = j / 384, k = j % 384;
        float v;
        if      (n < 128) v = Wq_s[k * 128 + n];
        else if (n < 256) v = Wk_s[k * 128 + (n - 128)];
        else if (n < 384) v = Wv_s[k * 128 + (n - 256)];
        else if (n < 480) v = Wq_p[k * 96  + (n - 384)];
        else if (n < 576) v = Wk_p[k * 96  + (n - 480)];
        else              v = Wv_p[k * 96  + (n - 576)];
        WallT[(size_t)n * 384 + k] = __float2bfloat16(v);
    }
}

// ---------------------------------------------------------------------------
// k_prep: Wout (1280,384) fp32 -> WoutT (384,1280) bf16, tiled LDS transpose
// ---------------------------------------------------------------------------
__global__ __launch_bounds__(256) void k_prep(const float* __restrict__ Wout,
                                              __hip_bfloat16* __restrict__ WoutT) {
    __shared__ float tile[64][65];
    const int tid = threadIdx.x;
    const int k0 = blockIdx.x * 64;   // 20 blocks
    const int n0 = blockIdx.y * 64;   // 6 blocks
#pragma unroll
    for (int s = 0; s < 16; ++s) {
        int idx = s * 256 + tid, kk = idx >> 6, nn = idx & 63;
        tile[kk][nn] = Wout[(size_t)(k0 + kk) * 384 + n0 + nn];
    }
    __syncthreads();
#pragma unroll
    for (int s = 0; s < 16; ++s) {
        int idx = s * 256 + tid, nn = idx >> 6, kk = idx & 63;
        WoutT[(size_t)(n0 + nn) * 1280 + k0 + kk] = __float2bfloat16(tile[kk][nn]);
    }
}

// ---------------------------------------------------------------------------
// k_projm: [1024,672] = xb[1024,384] @ Wall[384,672]  (bf16 MFMA, fp32 out)
// scalar cols (<384) -> q_s/k_s/v_s, point cols -> praw
// ---------------------------------------------------------------------------
__global__ __launch_bounds__(256) void k_projm(
    const __hip_bfloat16* __restrict__ xb, const __hip_bfloat16* __restrict__ WallT,
    float* __restrict__ q_s, float* __restrict__ k_s, float* __restrict__ v_s,
    float* __restrict__ praw) {
    __shared__ __align__(16) bf16_t As[64 * 40];
    __shared__ __align__(16) bf16_t Bs[48 * 40];
    const int tid = threadIdx.x;
    const int row0 = blockIdx.x * 64, col0 = blockIdx.y * 48;
    const int w = tid >> 6, lane = tid & 63;
    f32x4v acc[3] = {};

    for (int k0 = 0; k0 < 384; k0 += 32) {
        __syncthreads();
        {
            int rr = tid >> 2, q = tid & 3;
            *reinterpret_cast<int4*>(&As[rr * 40 + q * 8]) =
                *reinterpret_cast<const int4*>(&xb[(size_t)(row0 + rr) * 384 + k0 + q * 8]);
            if (tid < 192)
                *reinterpret_cast<int4*>(&Bs[rr * 40 + q * 8]) =
                    *reinterpret_cast<const int4*>(&WallT[(size_t)(col0 + rr) * 384 + k0 + q * 8]);
        }
        __syncthreads();
        const int m = lane & 15, kq = lane >> 4;
        bf16x8 af = *reinterpret_cast<const bf16x8*>(&As[(w * 16 + m) * 40 + kq * 8]);
#pragma unroll
        for (int c = 0; c < 3; ++c) {
            bf16x8 bfr = *reinterpret_cast<const bf16x8*>(&Bs[(c * 16 + m) * 40 + kq * 8]);
            acc[c] = __builtin_amdgcn_mfma_f32_16x16x32_bf16(af, bfr, acc[c], 0, 0, 0);
        }
    }
    const int colL = lane & 15, rbase = (lane >> 4) * 4;
#pragma unroll
    for (int c = 0; c < 3; ++c) {
        int col = col0 + c * 16 + colL;
#pragma unroll
        for (int rg = 0; rg < 4; ++rg) {
            int row = row0 + w * 16 + rbase + rg;
            float v = acc[c][rg];
            int bb = row >> 9, ll = row & 511;
            if (col < 384) {
                int kind = col >> 7, n = (col >> 4) & 7, d = col & 15;
                float* dst = (kind == 0) ? q_s : (kind == 1) ? k_s : v_s;
                dst[((size_t)(bb * NH + n) * L + ll) * DS + d] = v;
            } else {
                praw[(size_t)row * 288 + (col - 384)] = v;
            }
        }
    }
}

// ---------------------------------------------------------------------------
// k_euclid: praw (1024x288) -> q_p/k_p/v_p with forward euclid  x@r + t
// ---------------------------------------------------------------------------
__global__ __launch_bounds__(256) void k_euclid(
    const float* __restrict__ praw, const float* __restrict__ r, const float* __restrict__ t,
    float* __restrict__ q_p, float* __restrict__ k_p, float* __restrict__ v_p) {
    int idx = blockIdx.x * 256 + threadIdx.x;          // 294912 total
    int row = idx / 288, o = idx % 288;
    int arr = o / 96, oo = o % 96;
    int n = oo / 12, pc = oo % 12, p = pc / 3, c = pc % 3;
    const float* base = praw + (size_t)row * 288 + arr * 96 + n * 12 + p * 3;
    float acc = t[row * 3 + c];
#pragma unroll
    for (int k = 0; k < 3; ++k) acc += base[k] * r[row * 9 + k * 3 + c];
    float* dst = (arr == 0) ? q_p : (arr == 1) ? k_p : v_p;
    int bb = row >> 9, ll = row & 511;
    dst[((size_t)(bb * NH + n) * L + ll) * 12 + pc] = acc;
}

// ---------------------------------------------------------------------------
// k_attn: fused per-(b,i) attention. Async double-buffered e staging,
// wave-private tiles, zero barriers in the K-loop.
// ---------------------------------------------------------------------------
__device__ __forceinline__ void pf_tile(const float4* esrc4, int tile, float* dst,
                                        int w, int ell) {
    float4* dst4 = (float4*)dst;
    const float4* base = esrc4 + (size_t)tile * TJ * 32;
#pragma unroll
    for (int s = 0; s < 4; ++s) {
        int slot = (w * 4 + s) * 64 + ell;       // 0..1023, wave-contiguous
        int j = slot >> 5;                        // in-tile row (wave-private: w*8..w*8+7)
        int g = (slot & 31) ^ (j & 31);           // inverse xor swizzle on the source
        cp_g2l_16(base + (size_t)j * 32 + g, dst4 + slot);
    }
}

__global__ __launch_bounds__(256, 3) void k_attn(
    const float* __restrict__ e, const float* __restrict__ r, const float* __restrict__ t,
    const float* __restrict__ Wpb, const float* __restrict__ gamma,
    const float* __restrict__ q_s, const float* __restrict__ k_s, const float* __restrict__ v_s,
    const float* __restrict__ q_p, const float* __restrict__ k_p, const float* __restrict__ v_p,
    __hip_bfloat16* __restrict__ concat) {
    __shared__ __align__(16) float et0[TJ * DP];
    __shared__ __align__(16) float et1[TJ * DP];
    __shared__ __align__(16) float wpbT[8 * 132];
    __shared__ __align__(16) float pt [4 * 8 * 12];   // [w][n][j8]  (pad 12)
    __shared__ __align__(16) float ptT[4 * 8 * 8];    // [w][j8][n]
    __shared__ float sv[4 * 224];
    __shared__ __align__(16) float qsl[8 * 16];
    __shared__ __align__(16) float qpl[8 * 12];
    __shared__ float gsh[8], rtsh[12], lpart[32], lsh[8], osh[96], o2sh[96];

    const int tid = threadIdx.x;
    const int bi = blockIdx.x;
    const int b = bi >> 9, i = bi & 511, b8 = b * NH;
    const int w = tid >> 6, ell = tid & 63;
    const int nH = ell >> 3, j8 = ell & 7;        // logit: head, in-wave row
    const int d4 = ell & 31, jh = ell >> 5;       // out_pair ownership

    // ---- init shared state ----
    for (int idx = tid; idx < 1024; idx += 256)
        wpbT[(idx >> 7) * 132 + (idx & 127)] = Wpb[(idx & 127) * NH + (idx >> 7)];
    if (tid < 128) {
        int n = tid >> 4, d = tid & 15;
        qsl[n * 16 + d] = q_s[((size_t)(b8 + n) * L + i) * DS + d];
    } else if (tid < 224) {
        int o = tid - 128; int n = o / 12, pc = o % 12;
        qpl[n * 12 + pc] = q_p[((size_t)(b8 + n) * L + i) * 12 + pc];
    } else if (tid < 232) {
        gsh[tid - 224] = gamma[tid - 224];
    } else if (tid < 244) {
        int c = tid - 232;
        rtsh[c] = (c < 9) ? r[bi * 9 + c] : t[bi * 3 + (c - 9)];
    }

    // ---- per-lane SV item metadata ----
    int nIt[4]; const float* pIt[4]; int strIt[4];
#pragma unroll
    for (int it = 0; it < 4; ++it) {
        int ii = ell + it * 64;
        bool valid = (it < 3) || (ell < 32);
        if (!valid) { nIt[it] = 0; pIt[it] = v_s; strIt[it] = 16; continue; }
        if (ii < 128) {
            int n = ii >> 4;
            nIt[it] = n; strIt[it] = 16;
            pIt[it] = v_s + (((size_t)(b8 + n) * L + w * 8) << 4) + (ii & 15);
        } else {
            int o = ii - 128; int n = o / 12;
            nIt[it] = n; strIt[it] = 12;
            pIt[it] = v_p + ((size_t)(b8 + n) * L + w * 8) * 12 + (o % 12);
        }
    }

    const float4* esrc4 = reinterpret_cast<const float4*>(e + (size_t)(b * L + i) * L * DP);

    pf_tile(esrc4, 0, et0, w, ell);
    __syncthreads();   // init visible; pf(0) drained (vmcnt0 inside)

    float lsum = 0.f;
    float4 accPair[8];
#pragma unroll
    for (int n = 0; n < 8; ++n) accPair[n] = make_float4(0.f, 0.f, 0.f, 0.f);
    float accSV[4] = {0.f, 0.f, 0.f, 0.f};

#pragma unroll 2
    for (int tt = 0; tt < NTILE; ++tt) {
        float* cur = (tt & 1) ? et1 : et0;
        float* nxt = (tt & 1) ? et0 : et1;
        __builtin_amdgcn_s_waitcnt(0xF70);        // vmcnt(0): pf(tt) complete
        __builtin_amdgcn_sched_barrier(0);

        // ---- kv loads for this tile (issued BEFORE next prefetch) ----
        const int jg = tt * TJ + w * 8 + j8;      // global j for logit
        const float4* ksr = reinterpret_cast<const float4*>(k_s + (((size_t)(b8 + nH) * L + jg) << 4));
        float4 ks0 = ksr[0], ks1 = ksr[1], ks2 = ksr[2], ks3 = ksr[3];
        const float4* kpr = reinterpret_cast<const float4*>(k_p + ((size_t)(b8 + nH) * L + jg) * 12);
        float4 kp0 = kpr[0], kp1 = kpr[1], kp2 = kpr[2];
        float vv[4][8];
#pragma unroll
        for (int it = 0; it < 4; ++it)
            if (it < 3 || ell < 32) {
                const float* p = pIt[it] + (size_t)tt * TJ * strIt[it];
#pragma unroll
                for (int jj = 0; jj < 8; ++jj) vv[it][jj] = p[jj * strIt[it]];
            }
        __builtin_amdgcn_sched_barrier(0);
        if (tt < NTILE - 1) pf_tile(esrc4, tt + 1, nxt, w, ell);
        __builtin_amdgcn_sched_barrier(0);

        // ---- logit for (head nH, row w*8+j8) ----
        {
            const int jrow = w * 8 + j8;
            const float4* row4 = reinterpret_cast<const float4*>(cur) + (size_t)jrow * 32;
            const float4* wr4 = reinterpret_cast<const float4*>(&wpbT[nH * 132]);
            float bsum = 0.f;
#pragma unroll 8
            for (int g = 0; g < 32; ++g) {
                float4 ev = row4[g ^ (jrow & 31)];
                float4 wv4 = wr4[g];
                bsum += ev.x * wv4.x + ev.y * wv4.y + ev.z * wv4.z + ev.w * wv4.w;
            }
            const float4* q4 = reinterpret_cast<const float4*>(&qsl[nH * 16]);
            float4 qa = q4[0], qb = q4[1], qc = q4[2], qd = q4[3];
            float ssum = ks0.x * qa.x + ks0.y * qa.y + ks0.z * qa.z + ks0.w * qa.w
                       + ks1.x * qb.x + ks1.y * qb.y + ks1.z * qb.z + ks1.w * qb.w
                       + ks2.x * qc.x + ks2.y * qc.y + ks2.z * qc.z + ks2.w * qc.w
                       + ks3.x * qd.x + ks3.y * qd.y + ks3.z * qd.z + ks3.w * qd.w;
            const float4* qp4 = reinterpret_cast<const float4*>(&qpl[nH * 12]);
            float4 pa = qp4[0], pb = qp4[1], pc4 = qp4[2];
            float d0, sq = 0.f;
            d0 = pa.x - kp0.x; sq += d0 * d0;  d0 = pa.y - kp0.y; sq += d0 * d0;
            d0 = pa.z - kp0.z; sq += d0 * d0;  d0 = pa.w - kp0.w; sq += d0 * d0;
            d0 = pb.x - kp1.x; sq += d0 * d0;  d0 = pb.y - kp1.y; sq += d0 * d0;
            d0 = pb.z - kp1.z; sq += d0 * d0;  d0 = pb.w - kp1.w; sq += d0 * d0;
            d0 = pc4.x - kp2.x; sq += d0 * d0; d0 = pc4.y - kp2.y; sq += d0 * d0;
            d0 = pc4.z - kp2.z; sq += d0 * d0; d0 = pc4.w - kp2.w; sq += d0 * d0;
            float lg = SCALE_TOTAL * (ssum * SCALE_SCALAR + bsum
                                      - 0.5f * SCALE_POINT * gsh[nH] * sq);
            float pv = __expf(lg);
            lsum += pv;
            pt [w * 96 + nH * 12 + j8] = pv;
            ptT[w * 64 + j8 * 8 + nH] = pv;
        }

        // ---- out_pair accumulation (intra-wave pt) ----
        {
            const float4* cur4 = reinterpret_cast<const float4*>(cur);
#pragma unroll
            for (int s = 0; s < 4; ++s) {
                int jloc = jh * 4 + s;
                int jrow = w * 8 + jloc;
                float4 ev = cur4[jrow * 32 + (d4 ^ (jrow & 31))];
                const float4* pb4 = reinterpret_cast<const float4*>(&ptT[w * 64 + jloc * 8]);
                float4 pA = pb4[0], pB = pb4[1];
#define ACCP(nn, ps) accPair[nn].x += (ps) * ev.x; accPair[nn].y += (ps) * ev.y; \
                     accPair[nn].z += (ps) * ev.z; accPair[nn].w += (ps) * ev.w;
                ACCP(0, pA.x) ACCP(1, pA.y) ACCP(2, pA.z) ACCP(3, pA.w)
                ACCP(4, pB.x) ACCP(5, pB.y) ACCP(6, pB.z) ACCP(7, pB.w)
#undef ACCP
            }
        }

        // ---- out_scalar / out_point accumulation ----
#pragma unroll
        for (int it = 0; it < 4; ++it)
            if (it < 3 || ell < 32) {
                const float4* pr = reinterpret_cast<const float4*>(&pt[w * 96 + nIt[it] * 12]);
                float4 pA = pr[0], pB = pr[1];
                accSV[it] += pA.x * vv[it][0] + pA.y * vv[it][1] + pA.z * vv[it][2] + pA.w * vv[it][3]
                           + pB.x * vv[it][4] + pB.y * vv[it][5] + pB.z * vv[it][6] + pB.w * vv[it][7];
            }
    }

    // ---- epilogue ----
    lsum += __shfl_xor(lsum, 1);
    lsum += __shfl_xor(lsum, 2);
    lsum += __shfl_xor(lsum, 4);
    if (j8 == 0) lpart[w * 8 + nH] = lsum;
#pragma unroll
    for (int it = 0; it < 4; ++it)
        if (it < 3 || ell < 32) sv[w * 224 + ell + it * 64] = accSV[it];
    __syncthreads();                 // all tiles done (et free), sv/lpart visible

    float4* red4 = reinterpret_cast<float4*>(et0);
    {
        int owner = w * 2 + jh;
#pragma unroll
        for (int n = 0; n < 8; ++n) red4[(owner * 8 + n) * 32 + d4] = accPair[n];
    }
    __syncthreads();

    if (tid < 8) lsh[tid] = lpart[tid] + lpart[8 + tid] + lpart[16 + tid] + lpart[24 + tid];
    const int np = tid >> 5, gp = tid & 31;
    float4 ps = make_float4(0.f, 0.f, 0.f, 0.f);
#pragma unroll
    for (int o = 0; o < 8; ++o) {
        float4 v = red4[(o * 8 + np) * 32 + gp];
        ps.x += v.x; ps.y += v.y; ps.z += v.z; ps.w += v.w;
    }
    __syncthreads();                 // lsh ready

    __hip_bfloat16* crow = concat + (size_t)bi * DCAT;
    {
        float inv = 1.f / lsh[np];
        crow[128 + np * 128 + gp * 4 + 0] = __float2bfloat16(ps.x * inv);
        crow[128 + np * 128 + gp * 4 + 1] = __float2bfloat16(ps.y * inv);
        crow[128 + np * 128 + gp * 4 + 2] = __float2bfloat16(ps.z * inv);
        crow[128 + np * 128 + gp * 4 + 3] = __float2bfloat16(ps.w * inv);
    }
    if (tid < 128) {
        float vsum = sv[tid] + sv[224 + tid] + sv[448 + tid] + sv[672 + tid];
        crow[tid] = __float2bfloat16(vsum / lsh[tid >> 4]);
    } else if (tid < 224) {
        int o = tid - 128;
        float vsum = sv[tid] + sv[224 + tid] + sv[448 + tid] + sv[672 + tid];
        osh[o] = vsum / lsh[o / 12];
    }
    __syncthreads();
    if (tid < 96) {   // inverse euclid: o_c = sum_k (op_k - t_k) * r[c][k]
        int n = tid / 12, pc = tid % 12, p = pc / 3, c = pc % 3;
        float oc = 0.f;
#pragma unroll
        for (int k = 0; k < 3; ++k)
            oc += (osh[n * 12 + p * 3 + k] - rtsh[9 + k]) * rtsh[c * 3 + k];
        crow[1152 + tid] = __float2bfloat16(oc);
        o2sh[tid] = oc;
    }
    __syncthreads();
    if (tid < 32) {
        int n = tid >> 2, p = tid & 3;
        float vx = o2sh[n * 12 + p * 3], vy = o2sh[n * 12 + p * 3 + 1], vz = o2sh[n * 12 + p * 3 + 2];
        crow[1248 + tid] = __float2bfloat16(sqrtf(vx * vx + vy * vy + vz * vz));
    }
}

// ---------------------------------------------------------------------------
// k_out: bf16 MFMA GEMM: out[1024,384] = concat[1024,1280] @ Wout + bout
// ---------------------------------------------------------------------------
__global__ __launch_bounds__(256) void k_out(const __hip_bfloat16* __restrict__ A,
                                             const __hip_bfloat16* __restrict__ Bt,
                                             const float* __restrict__ bout,
                                             float* __restrict__ out) {
    __shared__ __align__(16) bf16_t At[64 * 40];
    __shared__ __align__(16) bf16_t Bs[64 * 40];
    const int tid = threadIdx.x;
    const int row0 = blockIdx.x * 64, col0 = blockIdx.y * 64;
    const int wv = tid >> 6, lane = tid & 63;
    f32x4v acc[4] = {};

    for (int k0 = 0; k0 < 1280; k0 += 32) {
        __syncthreads();
        {
            int rr = tid >> 2, q = tid & 3;
            *reinterpret_cast<int4*>(&At[rr * 40 + q * 8]) =
                *reinterpret_cast<const int4*>(&A[(size_t)(row0 + rr) * 1280 + k0 + q * 8]);
            *reinterpret_cast<int4*>(&Bs[rr * 40 + q * 8]) =
                *reinterpret_cast<const int4*>(&Bt[(size_t)(col0 + rr) * 1280 + k0 + q * 8]);
        }
        __syncthreads();
        const int m = lane & 15, kq = lane >> 4;
        bf16x8 af = *reinterpret_cast<const bf16x8*>(&At[(wv * 16 + m) * 40 + kq * 8]);
#pragma unroll
        for (int nt = 0; nt < 4; ++nt) {
            bf16x8 bfr = *reinterpret_cast<const bf16x8*>(&Bs[(nt * 16 + m) * 40 + kq * 8]);
            acc[nt] = __builtin_amdgcn_mfma_f32_16x16x32_bf16(af, bfr, acc[nt], 0, 0, 0);
        }
    }
    const int col_l = lane & 15, rbase = (lane >> 4) * 4;
#pragma unroll
    for (int nt = 0; nt < 4; ++nt) {
        int col = col0 + nt * 16 + col_l;
        float bo = bout[col];
#pragma unroll
        for (int rg = 0; rg < 4; ++rg) {
            int rowg = row0 + wv * 16 + rbase + rg;
            out[(size_t)rowg * 384 + col] = acc[nt][rg] + bo;
        }
    }
}

// ---------------------------------------------------------------------------
extern "C" void kernel_launch(void* const* d_in, const int* in_sizes, int n_in,
                              void* d_out, int out_size, void* d_ws, size_t ws_size,
                              hipStream_t stream) {
    const float* x     = (const float*)d_in[0];
    const float* e     = (const float*)d_in[1];
    const float* r     = (const float*)d_in[2];
    const float* t     = (const float*)d_in[3];
    const float* Wq_s  = (const float*)d_in[4];
    const float* Wk_s  = (const float*)d_in[5];
    const float* Wv_s  = (const float*)d_in[6];
    const float* Wpb   = (const float*)d_in[7];
    const float* Wq_p  = (const float*)d_in[8];
    const float* Wk_p  = (const float*)d_in[9];
    const float* Wv_p  = (const float*)d_in[10];
    const float* gamma = (const float*)d_in[11];
    const float* Wout  = (const float*)d_in[12];
    const float* bout  = (const float*)d_in[13];

    float* ws   = (float*)d_ws;
    float* q_s  = ws + 0;          // 131072
    float* k_s  = ws + 131072;     // 131072
    float* v_s  = ws + 262144;     // 131072
    float* q_p  = ws + 393216;     // 98304
    float* k_p  = ws + 491520;     // 98304
    float* v_p  = ws + 589824;     // 98304
    float* praw = ws + 688128;     // 294912
    __hip_bfloat16* xb     = (__hip_bfloat16*)((char*)d_ws + 3932160); // 393216 bf16
    __hip_bfloat16* WallT  = (__hip_bfloat16*)((char*)d_ws + 4718592); // 258048 bf16
    __hip_bfloat16* concat = (__hip_bfloat16*)((char*)d_ws + 5234688); // 1310720 bf16
    __hip_bfloat16* WoutT  = (__hip_bfloat16*)((char*)d_ws + 7856128); // 491520 bf16
    float* out = (float*)d_out;

    hipLaunchKernelGGL(k_pack, dim3(2544), dim3(256), 0, stream,
                       x, Wq_s, Wk_s, Wv_s, Wq_p, Wk_p, Wv_p, xb, WallT);
    hipLaunchKernelGGL(k_prep, dim3(20, 6), dim3(256), 0, stream, Wout, WoutT);
    hipLaunchKernelGGL(k_projm, dim3(16, 14), dim3(256), 0, stream,
                       xb, WallT, q_s, k_s, v_s, praw);
    hipLaunchKernelGGL(k_euclid, dim3(1152), dim3(256), 0, stream,
                       praw, r, t, q_p, k_p, v_p);
    hipLaunchKernelGGL(k_attn, dim3(1024), dim3(256), 0, stream,
                       e, r, t, Wpb, gamma, q_s, k_s, v_s, q_p, k_p, v_p, concat);
    hipLaunchKernelGGL(k_out, dim3(16, 6), dim3(256), 0, stream, concat, WoutT, bout, out);
}

// Round 3
// 485.720 us; speedup vs baseline: 1.8320x; 1.8320x over previous
//
#include <hip/hip_runtime.h>
#include <hip/hip_bf16.h>
#include <math.h>

#define NH 8
#define L 512
#define DP 128
#define DS 16
#define DCAT 1280
#define TJ 32            // j-rows of e per tile
#define NCHUNK 4         // blocks per (b,i) row
#define CJ 128           // j-rows per chunk (L / NCHUNK)
#define PSTRIDE 1280     // floats per partial row

#define SCALE_SCALAR 0.25f
#define SCALE_POINT  0.23570226039551584f   // (4.5*4)^-0.5
#define SCALE_TOTAL  0.5773502691896258f    // 3^-0.5

typedef __bf16 bf16_t;
typedef bf16_t bf16x8 __attribute__((ext_vector_type(8)));
typedef float  f32x4v __attribute__((ext_vector_type(4)));

// ---------------------------------------------------------------------------
// k_pack: x -> bf16 (row-major 1024x384), all six W -> WallT (672x384 bf16)
// ---------------------------------------------------------------------------
__global__ __launch_bounds__(256) void k_pack(
    const float* __restrict__ x,
    const float* __restrict__ Wq_s, const float* __restrict__ Wk_s, const float* __restrict__ Wv_s,
    const float* __restrict__ Wq_p, const float* __restrict__ Wk_p, const float* __restrict__ Wv_p,
    __hip_bfloat16* __restrict__ xb, __hip_bfloat16* __restrict__ WallT) {
    int idx = blockIdx.x * 256 + threadIdx.x;          // 651264 total
    const int T1 = 1024 * 384;
    if (idx < T1) {
        xb[idx] = __float2bfloat16(x[idx]);
    } else {
        int j = idx - T1;                              // 0 .. 258047
        int n = j / 384, k = j % 384;
        float v;
        if      (n < 128) v = Wq_s[k * 128 + n];
        else if (n < 256) v = Wk_s[k * 128 + (n - 128)];
        else if (n < 384) v = Wv_s[k * 128 + (n - 256)];
        else if (n < 480) v = Wq_p[k * 96  + (n - 384)];
        else if (n < 576) v = Wk_p[k * 96  + (n - 480)];
        else              v = Wv_p[k * 96  + (n - 576)];
        WallT[(size_t)n * 384 + k] = __float2bfloat16(v);
    }
}

// ---------------------------------------------------------------------------
// k_prep: Wout (1280,384) fp32 -> WoutT (384,1280) bf16, tiled LDS transpose
// ---------------------------------------------------------------------------
__global__ __launch_bounds__(256) void k_prep(const float* __restrict__ Wout,
                                              __hip_bfloat16* __restrict__ WoutT) {
    __shared__ float tile[64][65];
    const int tid = threadIdx.x;
    const int k0 = blockIdx.x * 64;   // 20 blocks
    const int n0 = blockIdx.y * 64;   // 6 blocks
#pragma unroll
    for (int s = 0; s < 16; ++s) {
        int idx = s * 256 + tid, kk = idx >> 6, nn = idx & 63;
        tile[kk][nn] = Wout[(size_t)(k0 + kk) * 384 + n0 + nn];
    }
    __syncthreads();
#pragma unroll
    for (int s = 0; s < 16; ++s) {
        int idx = s * 256 + tid, nn = idx >> 6, kk = idx & 63;
        WoutT[(size_t)(n0 + nn) * 1280 + k0 + kk] = __float2bfloat16(tile[kk][nn]);
    }
}

// ---------------------------------------------------------------------------
// k_projm: [1024,672] = xb[1024,384] @ Wall[384,672]  (bf16 MFMA, fp32 out)
// ---------------------------------------------------------------------------
__global__ __launch_bounds__(256) void k_projm(
    const __hip_bfloat16* __restrict__ xb, const __hip_bfloat16* __restrict__ WallT,
    float* __restrict__ q_s, float* __restrict__ k_s, float* __restrict__ v_s,
    float* __restrict__ praw) {
    __shared__ __align__(16) bf16_t As[64 * 40];
    __shared__ __align__(16) bf16_t Bs[48 * 40];
    const int tid = threadIdx.x;
    const int row0 = blockIdx.x * 64, col0 = blockIdx.y * 48;
    const int w = tid >> 6, lane = tid & 63;
    f32x4v acc[3] = {};

    for (int k0 = 0; k0 < 384; k0 += 32) {
        __syncthreads();
        {
            int rr = tid >> 2, q = tid & 3;
            *reinterpret_cast<int4*>(&As[rr * 40 + q * 8]) =
                *reinterpret_cast<const int4*>(&xb[(size_t)(row0 + rr) * 384 + k0 + q * 8]);
            if (tid < 192)
                *reinterpret_cast<int4*>(&Bs[rr * 40 + q * 8]) =
                    *reinterpret_cast<const int4*>(&WallT[(size_t)(col0 + rr) * 384 + k0 + q * 8]);
        }
        __syncthreads();
        const int m = lane & 15, kq = lane >> 4;
        bf16x8 af = *reinterpret_cast<const bf16x8*>(&As[(w * 16 + m) * 40 + kq * 8]);
#pragma unroll
        for (int c = 0; c < 3; ++c) {
            bf16x8 bfr = *reinterpret_cast<const bf16x8*>(&Bs[(c * 16 + m) * 40 + kq * 8]);
            acc[c] = __builtin_amdgcn_mfma_f32_16x16x32_bf16(af, bfr, acc[c], 0, 0, 0);
        }
    }
    const int colL = lane & 15, rbase = (lane >> 4) * 4;
#pragma unroll
    for (int c = 0; c < 3; ++c) {
        int col = col0 + c * 16 + colL;
#pragma unroll
        for (int rg = 0; rg < 4; ++rg) {
            int row = row0 + w * 16 + rbase + rg;
            float v = acc[c][rg];
            int bb = row >> 9, ll = row & 511;
            if (col < 384) {
                int kind = col >> 7, n = (col >> 4) & 7, d = col & 15;
                float* dst = (kind == 0) ? q_s : (kind == 1) ? k_s : v_s;
                dst[((size_t)(bb * NH + n) * L + ll) * DS + d] = v;
            } else {
                praw[(size_t)row * 288 + (col - 384)] = v;
            }
        }
    }
}

// ---------------------------------------------------------------------------
// k_euclid: praw (1024x288) -> q_p/k_p/v_p with forward euclid  x@r + t
// ---------------------------------------------------------------------------
__global__ __launch_bounds__(256) void k_euclid(
    const float* __restrict__ praw, const float* __restrict__ r, const float* __restrict__ t,
    float* __restrict__ q_p, float* __restrict__ k_p, float* __restrict__ v_p) {
    int idx = blockIdx.x * 256 + threadIdx.x;          // 294912 total
    int row = idx / 288, o = idx % 288;
    int arr = o / 96, oo = o % 96;
    int n = oo / 12, pc = oo % 12, p = pc / 3, c = pc % 3;
    const float* base = praw + (size_t)row * 288 + arr * 96 + n * 12 + p * 3;
    float acc = t[row * 3 + c];
#pragma unroll
    for (int k = 0; k < 3; ++k) acc += base[k] * r[row * 9 + k * 3 + c];
    float* dst = (arr == 0) ? q_p : (arr == 1) ? k_p : v_p;
    int bb = row >> 9, ll = row & 511;
    dst[((size_t)(bb * NH + n) * L + ll) * 12 + pc] = acc;
}

// ---------------------------------------------------------------------------
// k_attn: per (b,i,chunk) block — streams e rows [chunk*128, chunk*128+128)
// through LDS once, accumulates unnormalized softmax sums, writes partials.
// Grid 4096 = 16 blocks/CU: inter-block wave overlap hides barrier drains.
// ---------------------------------------------------------------------------
__global__ __launch_bounds__(256) void k_attn(
    const float* __restrict__ e, const float* __restrict__ Wpb, const float* __restrict__ gamma,
    const float* __restrict__ q_s, const float* __restrict__ k_s, const float* __restrict__ v_s,
    const float* __restrict__ q_p, const float* __restrict__ k_p, const float* __restrict__ v_p,
    float* __restrict__ part) {
    __shared__ __align__(16) float et[TJ * DP];     // e tile, xor-swizzled float4 groups
    __shared__ __align__(16) float wpbT[NH * DP];
    __shared__ float pt[NH][36];                    // [n][j] (+pad)
    __shared__ float ptT[TJ][NH];                   // [j][n]
    __shared__ __align__(16) float qsl[NH * 16];
    __shared__ __align__(16) float qpl[NH * 12];
    __shared__ float gsh[NH];

    const int tid = threadIdx.x;
    const int blk = blockIdx.x;
    const int bi = blk >> 2, chunk = blk & 3;
    const int b = bi >> 9, i = bi & 511, b8 = b * NH;
    const int nH = tid >> 5, jL = tid & 31;         // logit: head, in-tile row
    const int d4 = tid & 31, jsub = tid >> 5;       // out_pair: float4 group, j-subgroup

    for (int idx = tid; idx < NH * DP; idx += 256)
        wpbT[(idx >> 7) * DP + (idx & 127)] = Wpb[(idx & 127) * NH + (idx >> 7)];
    if (tid < 128) {
        int n = tid >> 4, d = tid & 15;
        qsl[n * 16 + d] = q_s[((size_t)(b8 + n) * L + i) * DS + d];
    } else if (tid < 224) {
        int o = tid - 128, n = o / 12, pc = o % 12;
        qpl[n * 12 + pc] = q_p[((size_t)(b8 + n) * L + i) * 12 + pc];
    } else if (tid < 232) {
        gsh[tid - 224] = gamma[tid - 224];
    }

    // sv ownership
    const int nS = tid >> 4, dS = tid & 15;                      // tid < 128
    const int oP = tid - 128;
    const int nP = (oP >= 0 && oP < 96) ? oP / 12 : 0;
    const int pcP = (oP >= 0 && oP < 96) ? oP % 12 : 0;
    const float* vsp = v_s + (((size_t)(b8 + nS) * L + chunk * CJ) << 4) + dS;
    const float* vpp = v_p + ((size_t)(b8 + nP) * L + chunk * CJ) * 12 + pcP;

    float lsum = 0.f;
    float4 accPair[NH];
#pragma unroll
    for (int n = 0; n < NH; ++n) accPair[n] = make_float4(0.f, 0.f, 0.f, 0.f);
    float accS = 0.f, accP = 0.f;

    const float4* esrc4 = reinterpret_cast<const float4*>(
        e + ((size_t)(b * L + i) * L + chunk * CJ) * DP);

    for (int tile = 0; tile < CJ / TJ; ++tile) {
        const int j0 = tile * TJ;
        __syncthreads();                 // previous tile fully consumed; init visible
        // --- stage 32 rows of e ---
#pragma unroll
        for (int s = 0; s < 4; ++s) {
            int idx = tid + s * 256;     // 0..1023
            int j = idx >> 5, g = idx & 31;
            float4 v = esrc4[(size_t)(j0 + j) * 32 + g];
            reinterpret_cast<float4*>(et)[j * 32 + (g ^ j)] = v;
        }
        __syncthreads();
        // --- logit for (head nH, row jL) ---
        {
            const int jg = chunk * CJ + j0 + jL;
            const float4* row4 = reinterpret_cast<const float4*>(et) + jL * 32;
            const float4* wr4 = reinterpret_cast<const float4*>(&wpbT[nH * DP]);
            float bsum = 0.f;
#pragma unroll 8
            for (int g = 0; g < 32; ++g) {
                float4 ev = row4[g ^ jL];
                float4 wv4 = wr4[g];
                bsum += ev.x * wv4.x + ev.y * wv4.y + ev.z * wv4.z + ev.w * wv4.w;
            }
            const float4* ksr = reinterpret_cast<const float4*>(k_s + (((size_t)(b8 + nH) * L + jg) << 4));
            const float4* q4 = reinterpret_cast<const float4*>(&qsl[nH * 16]);
            float ssum = 0.f;
#pragma unroll
            for (int g = 0; g < 4; ++g) {
                float4 kv = ksr[g], qv = q4[g];
                ssum += kv.x * qv.x + kv.y * qv.y + kv.z * qv.z + kv.w * qv.w;
            }
            const float4* kpr = reinterpret_cast<const float4*>(k_p + ((size_t)(b8 + nH) * L + jg) * 12);
            const float4* qp4 = reinterpret_cast<const float4*>(&qpl[nH * 12]);
            float sq = 0.f;
#pragma unroll
            for (int g = 0; g < 3; ++g) {
                float4 kv = kpr[g], qv = qp4[g];
                float d0;
                d0 = qv.x - kv.x; sq += d0 * d0;  d0 = qv.y - kv.y; sq += d0 * d0;
                d0 = qv.z - kv.z; sq += d0 * d0;  d0 = qv.w - kv.w; sq += d0 * d0;
            }
            float lg = SCALE_TOTAL * (ssum * SCALE_SCALAR + bsum
                                      - 0.5f * SCALE_POINT * gsh[nH] * sq);
            float pv = __expf(lg);
            lsum += pv;
            pt[nH][jL] = pv;
            ptT[jL][nH] = pv;
        }
        __syncthreads();
        // --- out_pair: 4 j-rows per thread ---
        {
            const float4* et4 = reinterpret_cast<const float4*>(et);
#pragma unroll
            for (int s = 0; s < 4; ++s) {
                int j = jsub * 4 + s;
                float4 ev = et4[j * 32 + (d4 ^ j)];
                const float4* pb4 = reinterpret_cast<const float4*>(&ptT[j][0]);
                float4 pA = pb4[0], pB = pb4[1];
#define ACCP(nn, ps) accPair[nn].x += (ps) * ev.x; accPair[nn].y += (ps) * ev.y; \
                     accPair[nn].z += (ps) * ev.z; accPair[nn].w += (ps) * ev.w;
                ACCP(0, pA.x) ACCP(1, pA.y) ACCP(2, pA.z) ACCP(3, pA.w)
                ACCP(4, pB.x) ACCP(5, pB.y) ACCP(6, pB.z) ACCP(7, pB.w)
#undef ACCP
            }
        }
        // --- out_scalar / out_point ---
        if (tid < 128) {
            const float* vp = vsp + (size_t)j0 * 16;
#pragma unroll
            for (int q = 0; q < 8; ++q) {
                float4 p4 = *reinterpret_cast<const float4*>(&pt[nS][q * 4]);
                accS += p4.x * vp[(q * 4 + 0) * 16] + p4.y * vp[(q * 4 + 1) * 16]
                      + p4.z * vp[(q * 4 + 2) * 16] + p4.w * vp[(q * 4 + 3) * 16];
            }
        } else if (tid < 224) {
            const float* vp = vpp + (size_t)j0 * 12;
#pragma unroll
            for (int q = 0; q < 8; ++q) {
                float4 p4 = *reinterpret_cast<const float4*>(&pt[nP][q * 4]);
                accP += p4.x * vp[(q * 4 + 0) * 12] + p4.y * vp[(q * 4 + 1) * 12]
                      + p4.z * vp[(q * 4 + 2) * 12] + p4.w * vp[(q * 4 + 3) * 12];
            }
        }
    }

    // ---- write partials ----
    float* prow = part + (size_t)blk * PSTRIDE;
    lsum += __shfl_xor(lsum, 1);  lsum += __shfl_xor(lsum, 2);
    lsum += __shfl_xor(lsum, 4);  lsum += __shfl_xor(lsum, 8);
    lsum += __shfl_xor(lsum, 16);
    if (jL == 0) prow[1248 + nH] = lsum;
    if (tid < 128) prow[1024 + tid] = accS;
    else if (tid < 224) prow[1152 + (tid - 128)] = accP;

    // pair reduction over 8 jsub groups (log rounds through et)
    float4* red4 = reinterpret_cast<float4*>(et);
    __syncthreads();
    if (jsub >= 4) {
#pragma unroll
        for (int n = 0; n < NH; ++n) red4[((jsub - 4) * NH + n) * 32 + d4] = accPair[n];
    }
    __syncthreads();
    if (jsub < 4) {
#pragma unroll
        for (int n = 0; n < NH; ++n) {
            float4 o = red4[(jsub * NH + n) * 32 + d4];
            accPair[n].x += o.x; accPair[n].y += o.y; accPair[n].z += o.z; accPair[n].w += o.w;
        }
    }
    __syncthreads();
    if (jsub == 2 || jsub == 3) {
#pragma unroll
        for (int n = 0; n < NH; ++n) red4[((jsub - 2) * NH + n) * 32 + d4] = accPair[n];
    }
    __syncthreads();
    if (jsub < 2) {
#pragma unroll
        for (int n = 0; n < NH; ++n) {
            float4 o = red4[(jsub * NH + n) * 32 + d4];
            accPair[n].x += o.x; accPair[n].y += o.y; accPair[n].z += o.z; accPair[n].w += o.w;
        }
    }
    __syncthreads();
    if (jsub == 1) {
#pragma unroll
        for (int n = 0; n < NH; ++n) red4[n * 32 + d4] = accPair[n];
    }
    __syncthreads();
    if (jsub == 0) {
#pragma unroll
        for (int n = 0; n < NH; ++n) {
            float4 o = red4[n * 32 + d4];
            accPair[n].x += o.x; accPair[n].y += o.y; accPair[n].z += o.z; accPair[n].w += o.w;
            *reinterpret_cast<float4*>(&prow[n * 128 + d4 * 4]) = accPair[n];
        }
    }
}

// ---------------------------------------------------------------------------
// k_comb: combine 4 chunk-partials per (b,i); normalize; epilogue; write concat
// ---------------------------------------------------------------------------
__global__ __launch_bounds__(256) void k_comb(
    const float* __restrict__ part, const float* __restrict__ r, const float* __restrict__ t,
    __hip_bfloat16* __restrict__ concat) {
    __shared__ float comb[1256];
    __shared__ float rtsh[12], osh[96], o2sh[96];
    const int tid = threadIdx.x;
    const int bi = blockIdx.x;
    const float* base = part + (size_t)bi * NCHUNK * PSTRIDE;
#pragma unroll
    for (int s = 0; s < 5; ++s) {
        int idx = tid + s * 256;
        if (idx < 1256)
            comb[idx] = base[idx] + base[PSTRIDE + idx] + base[2 * PSTRIDE + idx] + base[3 * PSTRIDE + idx];
    }
    if (tid >= 244 && tid < 256) {
        int c = tid - 244;
        rtsh[c] = (c < 9) ? r[bi * 9 + c] : t[bi * 3 + (c - 9)];
    }
    __syncthreads();
    __hip_bfloat16* crow = concat + (size_t)bi * DCAT;
    if (tid < 128) crow[tid] = __float2bfloat16(comb[1024 + tid] / comb[1248 + (tid >> 4)]);
    for (int idx = tid; idx < 1024; idx += 256)
        crow[128 + idx] = __float2bfloat16(comb[idx] / comb[1248 + (idx >> 7)]);
    if (tid >= 128 && tid < 224) {
        int o = tid - 128;
        osh[o] = comb[1152 + o] / comb[1248 + o / 12];
    }
    __syncthreads();
    if (tid < 96) {   // inverse euclid: o_c = sum_k (op_k - t_k) * r[c][k]
        int n = tid / 12, pc = tid % 12, p = pc / 3, c = pc % 3;
        float oc = 0.f;
#pragma unroll
        for (int k = 0; k < 3; ++k)
            oc += (osh[n * 12 + p * 3 + k] - rtsh[9 + k]) * rtsh[c * 3 + k];
        crow[1152 + tid] = __float2bfloat16(oc);
        o2sh[tid] = oc;
    }
    __syncthreads();
    if (tid < 32) {
        int n = tid >> 2, p = tid & 3;
        float vx = o2sh[n * 12 + p * 3], vy = o2sh[n * 12 + p * 3 + 1], vz = o2sh[n * 12 + p * 3 + 2];
        crow[1248 + tid] = __float2bfloat16(sqrtf(vx * vx + vy * vy + vz * vz));
    }
}

// ---------------------------------------------------------------------------
// k_out: bf16 MFMA GEMM: out[1024,384] = concat[1024,1280] @ Wout + bout
// ---------------------------------------------------------------------------
__global__ __launch_bounds__(256) void k_out(const __hip_bfloat16* __restrict__ A,
                                             const __hip_bfloat16* __restrict__ Bt,
                                             const float* __restrict__ bout,
                                             float* __restrict__ out) {
    __shared__ __align__(16) bf16_t At[64 * 40];
    __shared__ __align__(16) bf16_t Bs[64 * 40];
    const int tid = threadIdx.x;
    const int row0 = blockIdx.x * 64, col0 = blockIdx.y * 64;
    const int wv = tid >> 6, lane = tid & 63;
    f32x4v acc[4] = {};

    for (int k0 = 0; k0 < 1280; k0 += 32) {
        __syncthreads();
        {
            int rr = tid >> 2, q = tid & 3;
            *reinterpret_cast<int4*>(&At[rr * 40 + q * 8]) =
                *reinterpret_cast<const int4*>(&A[(size_t)(row0 + rr) * 1280 + k0 + q * 8]);
            *reinterpret_cast<int4*>(&Bs[rr * 40 + q * 8]) =
                *reinterpret_cast<const int4*>(&Bt[(size_t)(col0 + rr) * 1280 + k0 + q * 8]);
        }
        __syncthreads();
        const int m = lane & 15, kq = lane >> 4;
        bf16x8 af = *reinterpret_cast<const bf16x8*>(&At[(wv * 16 + m) * 40 + kq * 8]);
#pragma unroll
        for (int nt = 0; nt < 4; ++nt) {
            bf16x8 bfr = *reinterpret_cast<const bf16x8*>(&Bs[(nt * 16 + m) * 40 + kq * 8]);
            acc[nt] = __builtin_amdgcn_mfma_f32_16x16x32_bf16(af, bfr, acc[nt], 0, 0, 0);
        }
    }
    const int col_l = lane & 15, rbase = (lane >> 4) * 4;
#pragma unroll
    for (int nt = 0; nt < 4; ++nt) {
        int col = col0 + nt * 16 + col_l;
        float bo = bout[col];
#pragma unroll
        for (int rg = 0; rg < 4; ++rg) {
            int rowg = row0 + wv * 16 + rbase + rg;
            out[(size_t)rowg * 384 + col] = acc[nt][rg] + bo;
        }
    }
}

// ---------------------------------------------------------------------------
extern "C" void kernel_launch(void* const* d_in, const int* in_sizes, int n_in,
                              void* d_out, int out_size, void* d_ws, size_t ws_size,
                              hipStream_t stream) {
    const float* x     = (const float*)d_in[0];
    const float* e     = (const float*)d_in[1];
    const float* r     = (const float*)d_in[2];
    const float* t     = (const float*)d_in[3];
    const float* Wq_s  = (const float*)d_in[4];
    const float* Wk_s  = (const float*)d_in[5];
    const float* Wv_s  = (const float*)d_in[6];
    const float* Wpb   = (const float*)d_in[7];
    const float* Wq_p  = (const float*)d_in[8];
    const float* Wk_p  = (const float*)d_in[9];
    const float* Wv_p  = (const float*)d_in[10];
    const float* gamma = (const float*)d_in[11];
    const float* Wout  = (const float*)d_in[12];
    const float* bout  = (const float*)d_in[13];

    float* ws   = (float*)d_ws;
    float* q_s  = ws + 0;          // 131072
    float* k_s  = ws + 131072;     // 131072
    float* v_s  = ws + 262144;     // 131072
    float* q_p  = ws + 393216;     // 98304
    float* k_p  = ws + 491520;     // 98304
    float* v_p  = ws + 589824;     // 98304
    float* praw = ws + 688128;     // 294912
    __hip_bfloat16* xb     = (__hip_bfloat16*)((char*)d_ws + 3932160); // 393216 bf16
    __hip_bfloat16* WallT  = (__hip_bfloat16*)((char*)d_ws + 4718592); // 258048 bf16
    __hip_bfloat16* concat = (__hip_bfloat16*)((char*)d_ws + 5234688); // 1310720 bf16
    __hip_bfloat16* WoutT  = (__hip_bfloat16*)((char*)d_ws + 7856128); // 491520 bf16
    float* part = (float*)((char*)d_ws + 8847360);                     // 4096*1280 fp32
    float* out = (float*)d_out;

    hipLaunchKernelGGL(k_pack, dim3(2544), dim3(256), 0, stream,
                       x, Wq_s, Wk_s, Wv_s, Wq_p, Wk_p, Wv_p, xb, WallT);
    hipLaunchKernelGGL(k_prep, dim3(20, 6), dim3(256), 0, stream, Wout, WoutT);
    hipLaunchKernelGGL(k_projm, dim3(16, 14), dim3(256), 0, stream,
                       xb, WallT, q_s, k_s, v_s, praw);
    hipLaunchKernelGGL(k_euclid, dim3(1152), dim3(256), 0, stream,
                       praw, r, t, q_p, k_p, v_p);
    hipLaunchKernelGGL(k_attn, dim3(4096), dim3(256), 0, stream,
                       e, Wpb, gamma, q_s, k_s, v_s, q_p, k_p, v_p, part);
    hipLaunchKernelGGL(k_comb, dim3(1024), dim3(256), 0, stream,
                       part, r, t, concat);
    hipLaunchKernelGGL(k_out, dim3(16, 6), dim3(256), 0, stream, concat, WoutT, bout, out);
}